// Round 11
// baseline (1175.168 us; speedup 1.0000x reference)
//
#include <hip/hip_runtime.h>
#include <hip/hip_cooperative_groups.h>

namespace cg = cooperative_groups;

#define NN 1024

typedef float f32x8 __attribute__((ext_vector_type(8)));

// ---------------- workspace layout (floats) ----------------
// PH     : [896][1024][8] @ 0        Uin: @7340032  Utop: @7864320  Urt: @8388608
// Uout   : @8847360  P: @9371648  GXPin1: @9379840  GXPhid1: @9404416
// GXPout : @9428992  GXPin2: @9453568  GXPhid2: @9478144

struct Args {
    const int* A;
    const float* hidden0; const float* post0; const float* obs;
    const float* reward; const float* lr;
    const float* fiw; const float* fib;
    const float* fhw; const float* fhb;
    const float* fow; const float* fob;
    const float* gin_wih; const float* gin_whh; const float* gin_bih; const float* gin_bhh;
    const float* ghid_wih; const float* ghid_whh; const float* ghid_bih; const float* ghid_bhh;
    const float* gout_wih; const float* gout_whh; const float* gout_bih; const float* gout_bhh;
    float* PH; float* Uin; float* Utop; float* Urt; float* Uout; float* P;
    float* GXPin1; float* GXPhid1; float* GXPout; float* GXPin2; float* GXPhid2;
    float* out;
};

__device__ __forceinline__ float sigmoid_f(float x)
{
    return __fdividef(1.f, 1.f + __expf(-x));
}
__device__ __forceinline__ float tanh_f(float x)
{
    float ax = fabsf(x);
    float e  = __expf(-2.f * ax);
    float t  = __fdividef(1.f - e, 1.f + e);
    return copysignf(t, x);
}
__device__ __forceinline__ f32x8 ld8(const float* __restrict__ p) { return *(const f32x8*)p; }
__device__ __forceinline__ void st8(float* __restrict__ p, f32x8 v) { *(f32x8*)p = v; }

__device__ __forceinline__ f32x8 gru_core(const float* __restrict__ sWH,
                                          const float* __restrict__ sGX,
                                          const float* __restrict__ sBhh,
                                          f32x8 gr, f32x8 gz, f32x8 gn,
                                          f32x8 h, float lr)
{
    f32x8 upd;
#pragma unroll
    for (int d = 0; d < 8; ++d) {
        float hr = sBhh[d], hz = sBhh[8 + d], hn = sBhh[16 + d];
#pragma unroll
        for (int k = 0; k < 8; ++k) {
            hr = fmaf(sWH[d * 8 + k],        h[k], hr);
            hz = fmaf(sWH[(8 + d) * 8 + k],  h[k], hz);
            hn = fmaf(sWH[(16 + d) * 8 + k], h[k], hn);
        }
        float r  = sigmoid_f(sGX[d] + gr[d] + hr);
        float z  = sigmoid_f(sGX[8 + d] + gz[d] + hz);
        float nv = tanh_f(fmaf(r, hn, sGX[16 + d] + gn[d]));
        float g  = (1.f - z) * nv + z * h[d];
        upd[d] = fmaf(g, lr, h[d]);
    }
    return upd;
}

// sm: [0..191]=sWH(24x8), [192..215]=sGX, [216..239]=sBhh
__device__ __forceinline__ void stage_syn(float* sm, const float* __restrict__ P, int prerow,
                                          const float* __restrict__ Wih,
                                          const float* __restrict__ Whh,
                                          const float* __restrict__ Bih,
                                          const float* __restrict__ Bhh, float rew)
{
    int t = threadIdx.x;
    __syncthreads();
    if (t < 192) { int j = t >> 3, k = t & 7; sm[j * 8 + k] = Whh[j * 8 + k]; }
    else if (t < 216) {
        int j = t - 192;
        float g = Bih[j] + Wih[j * 17 + 16] * rew;
#pragma unroll
        for (int k = 0; k < 8; ++k) g = fmaf(Wih[j * 17 + k], P[prerow * 8 + k], g);
        sm[192 + j] = g;
        sm[216 + j] = Bhh[j];
    }
    __syncthreads();
}

// ---------------- phases ----------------

__device__ __forceinline__ void ph_prep(float* sm, const Args& a, int b)
{
    int t = threadIdx.x;
    int gid = b * 256 + t;
    float pv;
    if (gid < 512) {
        int i = gid >> 3, j = gid & 7;
        float rs = 0.f;
#pragma unroll
        for (int d = 0; d < 8; ++d) rs += a.fiw[j * 8 + d];
        pv = tanhf(a.obs[i] * rs + a.fib[j]);
    } else {
        pv = a.post0[gid];
    }
    a.P[gid] = pv;
    sm[t] = pv;
    __syncthreads();
    int c0 = b * 32;
    const float* W = nullptr; float* dst = nullptr;
    if (c0 >= 64 && c0 < 960) { W = a.gin_wih;  dst = a.GXPin1; }
    else if (c0 >= 960)       { W = a.ghid_wih; dst = a.GXPhid1; }
    if (dst) {
        for (int v = t; v < 768; v += 256) {
            int c = v / 24, j = v % 24;
            float g = 0.f;
#pragma unroll
            for (int k = 0; k < 8; ++k) g = fmaf(W[j * 17 + 8 + k], sm[c * 8 + k], g);
            dst[(c0 + c) * 24 + j] = g;
        }
    }
}

template <int TICK>
__device__ __forceinline__ void ph_syn_in(float* sm, const Args& a, int task)
{
    int r = task >> 2;
    stage_syn(sm, a.P, r, a.gin_wih, a.gin_whh, a.gin_bih, a.gin_bhh, a.reward[0]);
    int n = 64 + ((task & 3) << 8) + threadIdx.x;
    if (n < NN) {
        int e = (r * NN + n) * 8;
        if (!a.A[r * NN + n]) {
            if (TICK == 1) { f32x8 z{}; st8(a.PH + e, z); }
        } else {
            f32x8 h;
            if (TICK == 1) {
                h = ld8(a.hidden0 + e);
            } else {
                const float* src = a.Uin + e;
                if (a.A[(960 + r) * NN + n])     src = a.Uout + e;
                else if (a.A[(64 + r) * NN + n]) src = a.Utop + e;
                h = ld8(src);
            }
            const float* gxp = (TICK == 1 ? a.GXPin1 : a.GXPin2) + n * 24;
            f32x8 upd = gru_core(sm, sm + 192, sm + 216,
                                 ld8(gxp), ld8(gxp + 8), ld8(gxp + 16), h, a.lr[0]);
            f32x8 pre = ld8(a.P + r * 8);
            st8(a.PH + e, upd * pre);
            if (TICK == 1) st8(a.Uin + e, upd);
        }
    }
}

__device__ __forceinline__ void ph_syn_hid1(float* sm, const Args& a, int task)
{
    int l = task >> 2;
    stage_syn(sm, a.P, 64 + l, a.ghid_wih, a.ghid_whh, a.ghid_bih, a.ghid_bhh, a.reward[0]);
    int n = 64 + ((task & 3) << 8) + threadIdx.x;
    if (n < NN) {
        int e = (l * NN + n) * 8;
        if (!a.A[(64 + l) * NN + n]) {
            if (l >= 64) { f32x8 z{}; st8(a.PH + e, z); }
        } else {
            f32x8 h = ld8(a.hidden0 + ((64 + l) * NN + n) * 8);
            const float* gxp = a.GXPhid1 + n * 24;
            f32x8 upd = gru_core(sm, sm + 192, sm + 216,
                                 ld8(gxp), ld8(gxp + 8), ld8(gxp + 16), h, a.lr[0]);
            f32x8 pre = ld8(a.P + (64 + l) * 8);
            f32x8 out = upd * pre;
            st8(a.PH + e, out);
            if (l < 64) st8(a.Utop + e, upd);
            if (n >= 960) st8(a.Urt + (l * 64 + (n - 960)) * 8, upd);
        }
    }
}

__device__ __forceinline__ void ph_syn_out(float* sm, const Args& a, int task)
{
    int l = task >> 2;
    stage_syn(sm, a.P, 960 + l, a.gout_wih, a.gout_whh, a.gout_bih, a.gout_bhh, a.reward[0]);
    int n = 64 + ((task & 3) << 8) + threadIdx.x;
    if (n < NN && a.A[(960 + l) * NN + n]) {
        f32x8 h = ld8(a.hidden0 + ((960 + l) * NN + n) * 8);
        const float* gxp = a.GXPout + n * 24;
        f32x8 upd = gru_core(sm, sm + 192, sm + 216,
                             ld8(gxp), ld8(gxp + 8), ld8(gxp + 16), h, a.lr[0]);
        f32x8 pre = ld8(a.P + (960 + l) * 8);
        int e = (l * NN + n) * 8;
        st8(a.PH + e, upd * pre);
        st8(a.Uout + e, upd);
    }
}

__device__ __forceinline__ void ph_syn_hid2(float* sm, const Args& a, int task)
{
    float* sWH = sm; float* sBhh = sm + 192; float* sGX4 = sm + 216;   // [4][24]
    int t = threadIdx.x;
    __syncthreads();
    if (t < 192) { int j = t >> 3, k = t & 7; sWH[j * 8 + k] = a.ghid_whh[j * 8 + k]; }
    else if (t < 216) sBhh[t - 192] = a.ghid_bhh[t - 192];
    if (t < 96) {
        int rr = t / 24, j = t % 24;
        int l = task * 4 + rr;
        float g = a.ghid_bih[j] + a.ghid_wih[j * 17 + 16] * a.reward[0];
#pragma unroll
        for (int k = 0; k < 8; ++k)
            g = fmaf(a.ghid_wih[j * 17 + k], a.P[(64 + l) * 8 + k], g);
        sGX4[rr * 24 + j] = g;
    }
    __syncthreads();
    int rr = t >> 6, nn = t & 63;
    int l = task * 4 + rr, n = 960 + nn;
    if (a.A[(64 + l) * NN + n]) {
        const float* hp = (l < 832 && a.A[(128 + l) * NN + n])
                              ? (a.Urt + ((64 + l) * 64 + nn) * 8)
                              : (a.hidden0 + ((64 + l) * NN + n) * 8);
        f32x8 h = ld8(hp);
        const float* gxp = a.GXPhid2 + n * 24;
        f32x8 upd = gru_core(sWH, sGX4 + rr * 24, sBhh,
                             ld8(gxp), ld8(gxp + 8), ld8(gxp + 16), h, a.lr[0]);
        f32x8 pre = ld8(a.P + (64 + l) * 8);
        st8(a.PH + (l * NN + n) * 8, upd * pre);
    }
}

__device__ __forceinline__ void ph_sum_hid1(float* sm, const Args& a, int task)
{
    float* sS = sm; float* sP = sm + 256;
    int t = threadIdx.x;
    int c0 = 64 + task * 32;
    int base = c0 * 8 + t;
    float acc = 0.f;
    for (int r = 0; r < 64; ++r) acc += a.PH[r * 8192 + base];
    sS[t] = acc;
    __syncthreads();
    int j = t & 7;
    float z = a.fhb[j];
#pragma unroll
    for (int d = 0; d < 8; ++d) z = fmaf(sS[(t & ~7) | d], a.fhw[j * 8 + d], z);
    float pv = tanhf(z);
    a.P[base] = pv;
    sP[t] = pv;
    __syncthreads();
    for (int v = t; v < 768; v += 256) {
        int c = v / 24, jj = v % 24;
        float a1 = 0.f, a2 = 0.f, a3 = 0.f;
#pragma unroll
        for (int k = 0; k < 8; ++k) {
            float p = sP[c * 8 + k];
            a1 = fmaf(a.ghid_wih[jj * 17 + 8 + k], p, a1);
            a2 = fmaf(a.gout_wih[jj * 17 + 8 + k], p, a2);
            a3 = fmaf(a.gin_wih [jj * 17 + 8 + k], p, a3);
        }
        int o = (c0 + c) * 24 + jj;
        a.GXPhid1[o] = a1; a.GXPout[o] = a2; a.GXPin2[o] = a3;
    }
}

// full 896-row column sum + neuron over 4 cols starting col0+task*4; optional GXP.
__device__ __forceinline__ void ph_sum_full(float* sm, const Args& a, int col0, int task,
                                            const float* __restrict__ W,
                                            const float* __restrict__ b,
                                            float* GXPdst, const float* gWih)
{
    float* sA = sm;            // [8][32]
    float* sS = sm + 256;      // [32]
    float* sPn = sm + 288;     // [32]
    int t = threadIdx.x;
    __syncthreads();
    int chunk = t >> 5, col = (t >> 3) & 3, dim = t & 7;
    int gc0 = col0 + task * 4;
    int base = (gc0 + col) * 8 + dim;
    float acc = 0.f;
    for (int r = chunk * 112; r < chunk * 112 + 112; ++r) acc += a.PH[r * 8192 + base];
    sA[chunk * 32 + col * 8 + dim] = acc;
    __syncthreads();
    if (t < 32) {
        float s = 0.f;
#pragma unroll
        for (int c = 0; c < 8; ++c) s += sA[c * 32 + t];
        sS[t] = s;
    }
    __syncthreads();
    if (t < 32) {
        int cl = t >> 3, j = t & 7;
        float z = b[j];
#pragma unroll
        for (int d = 0; d < 8; ++d) z = fmaf(sS[cl * 8 + d], W[j * 8 + d], z);
        float pv = tanhf(z);
        a.P[(gc0 + cl) * 8 + j] = pv;
        sPn[t] = pv;
    }
    __syncthreads();
    if (GXPdst && t < 96) {
        int c = t / 24, j = t % 24;
        float g = 0.f;
#pragma unroll
        for (int k = 0; k < 8; ++k) g = fmaf(gWih[j * 17 + 8 + k], sPn[c * 8 + k], g);
        GXPdst[(gc0 + c) * 24 + j] = g;
    }
}

__device__ __forceinline__ void ph_argmax(float* sm, const Args& a)
{
    int t = threadIdx.x;
    if (t < 64) sm[t] = a.P[(960 + t) * 8];
    __syncthreads();
    if (t == 0) {
        int best = 0; float bv = sm[0];
        for (int j = 1; j < 64; ++j)
            if (sm[j] > bv) { bv = sm[j]; best = j; }   // strict > = first-index tie-break
        a.out[0] = (float)best;
    }
}

// ---------------- cooperative mega-kernel ----------------
__global__ void __launch_bounds__(256, 4)
k_mega(Args a)
{
    __shared__ float sm[512];
    cg::grid_group grid = cg::this_grid();
    const int bid = blockIdx.x;
    const int G = gridDim.x;

    if (bid < 32) ph_prep(sm, a, bid);
    grid.sync();
    if (bid < 256) ph_syn_in<1>(sm, a, bid);
    grid.sync();
    if (bid < 28) ph_sum_hid1(sm, a, bid);
    grid.sync();
    for (int task = bid; task < 3584; task += G) ph_syn_hid1(sm, a, task);
    grid.sync();
    if (bid < 16) ph_sum_full(sm, a, 960, bid, a.fow, a.fob, a.GXPhid2, a.ghid_wih);
    grid.sync();
    if (bid < 256) ph_syn_out(sm, a, bid);
    grid.sync();
    if (bid < 256) ph_syn_in<2>(sm, a, bid);
    grid.sync();
    if (bid < 224) ph_sum_full(sm, a, 64, bid, a.fhw, a.fhb, nullptr, nullptr);
    grid.sync();
    if (bid < 224) ph_syn_hid2(sm, a, bid);
    grid.sync();
    if (bid < 16) ph_sum_full(sm, a, 960, bid, a.fow, a.fob, nullptr, nullptr);
    grid.sync();
    if (bid == 0) ph_argmax(sm, a);
}

// ---------------- fallback wrappers (round-6 equivalent chain) ----------------
__global__ void __launch_bounds__(256, 4) kw_prep(Args a)     { __shared__ float sm[512]; ph_prep(sm, a, blockIdx.x); }
__global__ void __launch_bounds__(256, 4) kw_syn_in1(Args a)  { __shared__ float sm[512]; ph_syn_in<1>(sm, a, blockIdx.x); }
__global__ void __launch_bounds__(256, 4) kw_syn_in2(Args a)  { __shared__ float sm[512]; ph_syn_in<2>(sm, a, blockIdx.x); }
__global__ void __launch_bounds__(256, 4) kw_sum_hid1(Args a) { __shared__ float sm[512]; ph_sum_hid1(sm, a, blockIdx.x); }
__global__ void __launch_bounds__(256, 4) kw_syn_hid1(Args a) { __shared__ float sm[512]; ph_syn_hid1(sm, a, blockIdx.x); }
__global__ void __launch_bounds__(256, 4) kw_syn_out(Args a)  { __shared__ float sm[512]; ph_syn_out(sm, a, blockIdx.x); }
__global__ void __launch_bounds__(256, 4) kw_syn_hid2(Args a) { __shared__ float sm[512]; ph_syn_hid2(sm, a, blockIdx.x); }
__global__ void __launch_bounds__(256, 4) kw_sum_out_gxp(Args a)
{ __shared__ float sm[512]; ph_sum_full(sm, a, 960, blockIdx.x, a.fow, a.fob, a.GXPhid2, a.ghid_wih); }
__global__ void __launch_bounds__(256, 4) kw_sum_hid2(Args a)
{ __shared__ float sm[512]; ph_sum_full(sm, a, 64, blockIdx.x, a.fhw, a.fhb, nullptr, nullptr); }
__global__ void __launch_bounds__(256, 4) kw_sum_out(Args a)
{ __shared__ float sm[512]; ph_sum_full(sm, a, 960, blockIdx.x, a.fow, a.fob, nullptr, nullptr); }
__global__ void __launch_bounds__(64) kw_argmax(Args a) { __shared__ float sm[64]; ph_argmax(sm, a); }

extern "C" void kernel_launch(void* const* d_in, const int* in_sizes, int n_in,
                              void* d_out, int out_size, void* d_ws, size_t ws_size,
                              hipStream_t stream)
{
    Args a;
    a.obs      = (const float*)d_in[0];
    a.reward   = (const float*)d_in[1];
    a.A        = (const int*)d_in[2];
    a.hidden0  = (const float*)d_in[3];
    a.post0    = (const float*)d_in[4];
    a.lr       = (const float*)d_in[5];
    a.fiw      = (const float*)d_in[6];
    a.fib      = (const float*)d_in[7];
    a.fhw      = (const float*)d_in[8];
    a.fhb      = (const float*)d_in[9];
    a.fow      = (const float*)d_in[10];
    a.fob      = (const float*)d_in[11];
    a.gin_wih  = (const float*)d_in[12];
    a.gin_whh  = (const float*)d_in[13];
    a.gin_bih  = (const float*)d_in[14];
    a.gin_bhh  = (const float*)d_in[15];
    a.ghid_wih = (const float*)d_in[16];
    a.ghid_whh = (const float*)d_in[17];
    a.ghid_bih = (const float*)d_in[18];
    a.ghid_bhh = (const float*)d_in[19];
    a.gout_wih = (const float*)d_in[20];
    a.gout_whh = (const float*)d_in[21];
    a.gout_bih = (const float*)d_in[22];
    a.gout_bhh = (const float*)d_in[23];

    float* ws  = (float*)d_ws;
    a.PH      = ws;
    a.Uin     = ws + 7340032;
    a.Utop    = a.Uin + 524288;
    a.Urt     = a.Utop + 524288;
    a.Uout    = a.Urt + 458752;
    a.P       = a.Uout + 524288;
    a.GXPin1  = a.P + 8192;
    a.GXPhid1 = a.GXPin1 + 24576;
    a.GXPout  = a.GXPhid1 + 24576;
    a.GXPin2  = a.GXPout + 24576;
    a.GXPhid2 = a.GXPin2 + 24576;
    a.out     = (float*)d_out;

    void* params[] = { (void*)&a };
    hipError_t err = hipLaunchCooperativeKernel((const void*)k_mega, dim3(1024), dim3(256),
                                                params, 0, stream);
    if (err != hipSuccess) {
        (void)hipGetLastError();   // clear sticky error; fall back to kernel chain
        kw_prep<<<32, 256, 0, stream>>>(a);
        kw_syn_in1<<<256, 256, 0, stream>>>(a);
        kw_sum_hid1<<<28, 256, 0, stream>>>(a);
        kw_syn_hid1<<<3584, 256, 0, stream>>>(a);
        kw_sum_out_gxp<<<16, 256, 0, stream>>>(a);
        kw_syn_out<<<256, 256, 0, stream>>>(a);
        kw_syn_in2<<<256, 256, 0, stream>>>(a);
        kw_sum_hid2<<<224, 256, 0, stream>>>(a);
        kw_syn_hid2<<<224, 256, 0, stream>>>(a);
        kw_sum_out<<<16, 256, 0, stream>>>(a);
        kw_argmax<<<1, 64, 0, stream>>>(a);
    }
}

// Round 13
// 88.675 us; speedup vs baseline: 13.2524x; 13.2524x over previous
//
#include <hip/hip_runtime.h>

#define NN 1024

typedef float f32x8 __attribute__((ext_vector_type(8)));
typedef float f32v4 __attribute__((ext_vector_type(4)));   // native vector for nt builtins

// ---------------- workspace layout (floats) ----------------
// PH     : [896][1024][8] @ 0        (7340032)
// Uin    : [64][1024][8]  @ 7340032  (524288)
// Utop   : [64][1024][8]  @ 7864320  (524288)
// Urt    : [896][64][8]   @ 8388608  (458752)
// Uout   : [64][1024][8]  @ 8847360  (524288)
// P      : [1024][8]      @ 9371648  (8192)
// GXPin1 : [1024][24]     @ 9379840  gin  over P0
// GXPhid1: [1024][24]     @ 9404416  ghid over P1 (+post0 tail)
// GXPout : [1024][24]     @ 9428992  gout over P2
// GXPin2 : [1024][24]     @ 9453568  gin  over P2
// GXPhid2: [1024][24]     @ 9478144  ghid over P3 (cols 960..)

__device__ __forceinline__ float sigmoid_f(float x)
{
    return __fdividef(1.f, 1.f + __expf(-x));
}
__device__ __forceinline__ float tanh_f(float x)
{
    float ax = fabsf(x);
    float e  = __expf(-2.f * ax);
    float t  = __fdividef(1.f - e, 1.f + e);
    return copysignf(t, x);
}
__device__ __forceinline__ f32x8 ld8(const float* __restrict__ p) { return *(const f32x8*)p; }
__device__ __forceinline__ void st8(float* __restrict__ p, f32x8 v) { *(f32x8*)p = v; }

// non-temporal 32B load (read-once streams: hidden0)
__device__ __forceinline__ f32x8 ldnt8(const float* __restrict__ p)
{
    f32v4 a = __builtin_nontemporal_load((const f32v4*)p);
    f32v4 b = __builtin_nontemporal_load(((const f32v4*)p) + 1);
    f32x8 r;
    r[0] = a.x; r[1] = a.y; r[2] = a.z; r[3] = a.w;
    r[4] = b.x; r[5] = b.y; r[6] = b.z; r[7] = b.w;
    return r;
}
// non-temporal 32B store (write-once, far-reuse: PH rows>=64)
__device__ __forceinline__ void stnt8(float* __restrict__ p, f32x8 v)
{
    f32v4 a, b;
    a.x = v[0]; a.y = v[1]; a.z = v[2]; a.w = v[3];
    b.x = v[4]; b.y = v[5]; b.z = v[6]; b.w = v[7];
    __builtin_nontemporal_store(a, (f32v4*)p);
    __builtin_nontemporal_store(b, ((f32v4*)p) + 1);
}

// gx = sGX[j] (row part) + g{r,z,n}[d] (col part, in regs); gh = sBhh[j] + Whh[j]·h
__device__ __forceinline__ f32x8 gru_core(const float (*__restrict__ sWH)[8],
                                          const float* __restrict__ sGX,
                                          const float* __restrict__ sBhh,
                                          f32x8 gr, f32x8 gz, f32x8 gn,
                                          f32x8 h, float lr)
{
    f32x8 upd;
#pragma unroll
    for (int d = 0; d < 8; ++d) {
        float hr = sBhh[d], hz = sBhh[8 + d], hn = sBhh[16 + d];
#pragma unroll
        for (int k = 0; k < 8; ++k) {
            hr = fmaf(sWH[d][k],      h[k], hr);
            hz = fmaf(sWH[8 + d][k],  h[k], hz);
            hn = fmaf(sWH[16 + d][k], h[k], hn);
        }
        float r  = sigmoid_f(sGX[d] + gr[d] + hr);
        float z  = sigmoid_f(sGX[8 + d] + gz[d] + hz);
        float nv = tanh_f(fmaf(r, hn, sGX[16 + d] + gn[d]));
        float g  = (1.f - z) * nv + z * h[d];
        upd[d] = fmaf(g, lr, h[d]);
    }
    return upd;
}

#define SYN_STAGE(PREROW)                                                               \
    __shared__ float sWH[24][8]; __shared__ float sGX[24]; __shared__ float sBhh[24];   \
    { int t_ = threadIdx.x;                                                             \
      if (t_ < 192) { int j = t_ >> 3, k = t_ & 7; sWH[j][k] = Whh[j * 8 + k]; }        \
      else if (t_ < 216) { int j = t_ - 192;                                            \
        float a = Bih[j] + Wih[j * 17 + 16] * reward[0];                                \
        _Pragma("unroll") for (int k = 0; k < 8; ++k)                                   \
            a = fmaf(Wih[j * 17 + k], P[(PREROW) * 8 + k], a);                          \
        sGX[j] = a; sBhh[j] = Bhh[j]; }                                                 \
      __syncthreads(); }

// P init + GXPin1 (gin over P0) + GXPhid1 tail (ghid over post0, cols 960..)
__global__ void __launch_bounds__(256)
k_prep(const float* __restrict__ obs, const float* __restrict__ fiw,
       const float* __restrict__ fib, const float* __restrict__ post0,
       float* __restrict__ P, float* __restrict__ GXPin1, float* __restrict__ GXPhid1,
       const float* __restrict__ gin_wih, const float* __restrict__ ghid_wih)
{
    int t = threadIdx.x, b = blockIdx.x;
    int gid = b * 256 + t;
    float pv;
    if (gid < 512) {
        int i = gid >> 3, j = gid & 7;
        float rs = 0.f;
#pragma unroll
        for (int d = 0; d < 8; ++d) rs += fiw[j * 8 + d];
        pv = tanhf(obs[i] * rs + fib[j]);
    } else {
        pv = post0[gid];
    }
    P[gid] = pv;
    __shared__ float sP[256];
    sP[t] = pv;
    __syncthreads();
    int c0 = b * 32;
    const float* W = nullptr; float* dst = nullptr;
    if (c0 >= 64 && c0 < 960) { W = gin_wih;  dst = GXPin1; }
    else if (c0 >= 960)       { W = ghid_wih; dst = GXPhid1; }
    if (dst) {
        for (int v = t; v < 768; v += 256) {
            int c = v / 24, j = v % 24;
            float a = 0.f;
#pragma unroll
            for (int k = 0; k < 8; ++k) a = fmaf(W[j * 17 + 8 + k], sP[c * 8 + k], a);
            dst[(c0 + c) * 24 + j] = a;
        }
    }
}

// input-layer syn: row r=bid>>2 (<64), cols 64..1024. TICK1 zero-fills inactive.
template <int TICK>
__global__ void __launch_bounds__(256, 4)
k_syn_in(const int* __restrict__ A, const float* __restrict__ hidden0,
         const float* __restrict__ P, float* __restrict__ PH,
         float* __restrict__ Uin, const float* __restrict__ Utop,
         const float* __restrict__ Uout, const float* __restrict__ GXP,
         const float* __restrict__ Wih, const float* __restrict__ Whh,
         const float* __restrict__ Bih, const float* __restrict__ Bhh,
         const float* __restrict__ reward, const float* __restrict__ lr)
{
    int r = blockIdx.x >> 2;
    SYN_STAGE(r);
    int n = 64 + ((blockIdx.x & 3) << 8) + threadIdx.x;
    if (n >= NN) return;
    int e = (r * NN + n) * 8;
    if (!A[r * NN + n]) {
        if (TICK == 1) { f32x8 z{}; st8(PH + e, z); }
        return;
    }
    f32x8 h;
    if (TICK == 1) {
        h = ldnt8(hidden0 + e);
    } else {
        const float* src = Uin + e;
        if (A[(960 + r) * NN + n])     src = Uout + e;
        else if (A[(64 + r) * NN + n]) src = Utop + e;
        h = ld8(src);
    }
    const float* gxp = GXP + n * 24;
    f32x8 upd = gru_core(sWH, sGX, sBhh, ld8(gxp), ld8(gxp + 8), ld8(gxp + 16), h, lr[0]);
    f32x8 pre = ld8(P + r * 8);
    st8(PH + e, upd * pre);
    if (TICK == 1) st8(Uin + e, upd);
}

// hidden syn tick1: row l=bid>>2 (<896), cols 64..1024.
// l<64 skip-if-inactive (preserve in-syn); l>=64 zero-if-inactive (nt store).
__global__ void __launch_bounds__(256, 4)
k_syn_hid1(const int* __restrict__ A, const float* __restrict__ hidden0,
           const float* __restrict__ P, float* __restrict__ PH,
           float* __restrict__ Utop, float* __restrict__ Urt,
           const float* __restrict__ GXP,
           const float* __restrict__ Wih, const float* __restrict__ Whh,
           const float* __restrict__ Bih, const float* __restrict__ Bhh,
           const float* __restrict__ reward, const float* __restrict__ lr)
{
    int l = blockIdx.x >> 2;
    SYN_STAGE(64 + l);
    int n = 64 + ((blockIdx.x & 3) << 8) + threadIdx.x;
    if (n >= NN) return;
    int e = (l * NN + n) * 8;
    if (!A[(64 + l) * NN + n]) {
        if (l >= 64) { f32x8 z{}; stnt8(PH + e, z); }
        return;
    }
    f32x8 h = ldnt8(hidden0 + ((64 + l) * NN + n) * 8);
    const float* gxp = GXP + n * 24;
    f32x8 upd = gru_core(sWH, sGX, sBhh, ld8(gxp), ld8(gxp + 8), ld8(gxp + 16), h, lr[0]);
    f32x8 pre = ld8(P + (64 + l) * 8);
    f32x8 out = upd * pre;
    if (l < 64) { st8(PH + e, out); st8(Utop + e, upd); }
    else        { stnt8(PH + e, out); }
    if (n >= 960) st8(Urt + (l * 64 + (n - 960)) * 8, upd);
}

// output syn tick1: row 960+l, writes PH rows l<64; skip-if-inactive.
__global__ void __launch_bounds__(256, 4)
k_syn_out(const int* __restrict__ A, const float* __restrict__ hidden0,
          const float* __restrict__ P, float* __restrict__ PH,
          float* __restrict__ Uout, const float* __restrict__ GXP,
          const float* __restrict__ Wih, const float* __restrict__ Whh,
          const float* __restrict__ Bih, const float* __restrict__ Bhh,
          const float* __restrict__ reward, const float* __restrict__ lr)
{
    int l = blockIdx.x >> 2;
    SYN_STAGE(960 + l);
    int n = 64 + ((blockIdx.x & 3) << 8) + threadIdx.x;
    if (n >= NN) return;
    if (!A[(960 + l) * NN + n]) return;
    f32x8 h = ldnt8(hidden0 + ((960 + l) * NN + n) * 8);
    const float* gxp = GXP + n * 24;
    f32x8 upd = gru_core(sWH, sGX, sBhh, ld8(gxp), ld8(gxp + 8), ld8(gxp + 16), h, lr[0]);
    f32x8 pre = ld8(P + (960 + l) * 8);
    int e = (l * NN + n) * 8;
    st8(PH + e, upd * pre);
    st8(Uout + e, upd);
}

// hidden syn tick2: rows 0..896, cols 960..1024 only; skip-if-inactive. 4 rows/block.
__global__ void __launch_bounds__(256, 4)
k_syn_hid2(const int* __restrict__ A, const float* __restrict__ hidden0,
           const float* __restrict__ P, float* __restrict__ PH,
           const float* __restrict__ Urt, const float* __restrict__ GXP,
           const float* __restrict__ Wih, const float* __restrict__ Whh,
           const float* __restrict__ Bih, const float* __restrict__ Bhh,
           const float* __restrict__ reward, const float* __restrict__ lr)
{
    __shared__ float sWH[24][8]; __shared__ float sBhh[24]; __shared__ float sGX4[4][24];
    int t = threadIdx.x;
    if (t < 192) { int j = t >> 3, k = t & 7; sWH[j][k] = Whh[j * 8 + k]; }
    else if (t < 216) sBhh[t - 192] = Bhh[t - 192];
    if (t < 96) {
        int rr = t / 24, j = t % 24;
        int l = blockIdx.x * 4 + rr;
        float a = Bih[j] + Wih[j * 17 + 16] * reward[0];
#pragma unroll
        for (int k = 0; k < 8; ++k) a = fmaf(Wih[j * 17 + k], P[(64 + l) * 8 + k], a);
        sGX4[rr][j] = a;
    }
    __syncthreads();
    int rr = t >> 6, nn = t & 63;
    int l = blockIdx.x * 4 + rr, n = 960 + nn;
    if (!A[(64 + l) * NN + n]) return;
    const float* hp = (l < 832 && A[(128 + l) * NN + n]) ? (Urt + ((64 + l) * 64 + nn) * 8)
                                                         : (hidden0 + ((64 + l) * NN + n) * 8);
    f32x8 h = ld8(hp);
    const float* gxp = GXP + n * 24;
    f32x8 upd = gru_core(sWH, sGX4[rr], sBhh, ld8(gxp), ld8(gxp + 8), ld8(gxp + 16), h, lr[0]);
    f32x8 pre = ld8(P + (64 + l) * 8);
    st8(PH + (l * NN + n) * 8, upd * pre);
}

// tick1 hidden neuron: sum PH rows 0..64, cols 64..960; fused neuron + 3x GXP production.
__global__ void __launch_bounds__(256)
k_sum_hid1(const float* __restrict__ PH, float* __restrict__ P,
           const float* __restrict__ W, const float* __restrict__ b,
           float* __restrict__ GXPhid1, float* __restrict__ GXPout,
           float* __restrict__ GXPin2,
           const float* __restrict__ ghid_wih, const float* __restrict__ gout_wih,
           const float* __restrict__ gin_wih)
{
    int t = threadIdx.x;
    int c0 = 64 + blockIdx.x * 32;
    int base = c0 * 8 + t;
    float acc = 0.f;
    for (int r = 0; r < 64; ++r) acc += PH[r * 8192 + base];
    __shared__ float sS[256];
    sS[t] = acc; __syncthreads();
    int j = t & 7;
    float z = b[j];
#pragma unroll
    for (int d = 0; d < 8; ++d) z = fmaf(sS[(t & ~7) | d], W[j * 8 + d], z);
    float pv = tanhf(z);
    P[base] = pv;
    __shared__ float sP[256];
    sP[t] = pv; __syncthreads();
    for (int v = t; v < 768; v += 256) {
        int c = v / 24, jj = v % 24;
        float a1 = 0.f, a2 = 0.f, a3 = 0.f;
#pragma unroll
        for (int k = 0; k < 8; ++k) {
            float p = sP[c * 8 + k];
            a1 = fmaf(ghid_wih[jj * 17 + 8 + k], p, a1);
            a2 = fmaf(gout_wih[jj * 17 + 8 + k], p, a2);
            a3 = fmaf(gin_wih [jj * 17 + 8 + k], p, a3);
        }
        int o = (c0 + c) * 24 + jj;
        GXPhid1[o] = a1; GXPout[o] = a2; GXPin2[o] = a3;
    }
}

// full 896-row column sum + neuron, cols 64..960 (8 cols/block, 512 thr).
__global__ void __launch_bounds__(512)
k_sum_full(const float* __restrict__ PH, float* __restrict__ P,
           const float* __restrict__ W, const float* __restrict__ b)
{
    int t = threadIdx.x;
    int col = (t >> 3) & 7, dim = t & 7, chunk = t >> 6;
    int gc0 = 64 + blockIdx.x * 8;
    float acc = 0.f;
    int base = (gc0 + col) * 8 + dim;
    for (int r = chunk * 112; r < chunk * 112 + 112; ++r) acc += PH[r * 8192 + base];
    __shared__ float sA[8][64];
    sA[chunk][(col << 3) | dim] = acc;
    __syncthreads();
    __shared__ float sS[64];
    if (t < 64) {
        float s = 0.f;
#pragma unroll
        for (int c = 0; c < 8; ++c) s += sA[c][t];
        sS[t] = s;
    }
    __syncthreads();
    if (t < 64) {
        int cl = t >> 3, j = t & 7;
        float z = b[j];
#pragma unroll
        for (int d = 0; d < 8; ++d) z = fmaf(sS[(cl << 3) | d], W[j * 8 + d], z);
        P[(gc0 + cl) * 8 + j] = tanhf(z);
    }
}

// 896-row column sum + neuron over cols 960.. ; 256 thr, 4 cols/block, 16 blocks.
template <bool DO_GXP>
__global__ void __launch_bounds__(256)
k_sum_out(const float* __restrict__ PH, float* __restrict__ P,
          const float* __restrict__ W, const float* __restrict__ b,
          float* __restrict__ GXPdst, const float* __restrict__ gWih)
{
    int t = threadIdx.x;
    int chunk = t >> 5, col = (t >> 3) & 3, dim = t & 7;
    int gc0 = 960 + blockIdx.x * 4;
    float acc = 0.f;
    int base = (gc0 + col) * 8 + dim;
    for (int r = chunk * 112; r < chunk * 112 + 112; ++r) acc += PH[r * 8192 + base];
    __shared__ float sA[8][32];
    sA[chunk][(col << 3) | dim] = acc;
    __syncthreads();
    __shared__ float sS[32];
    if (t < 32) {
        float s = 0.f;
#pragma unroll
        for (int c = 0; c < 8; ++c) s += sA[c][t];
        sS[t] = s;
    }
    __syncthreads();
    __shared__ float sPn[32];
    if (t < 32) {
        int cl = t >> 3, j = t & 7;
        float z = b[j];
#pragma unroll
        for (int d = 0; d < 8; ++d) z = fmaf(sS[(cl << 3) | d], W[j * 8 + d], z);
        float pv = tanhf(z);
        P[(gc0 + cl) * 8 + j] = pv;
        sPn[t] = pv;
    }
    __syncthreads();
    if (DO_GXP && t < 96) {
        int c = t / 24, j = t % 24;
        float a = 0.f;
#pragma unroll
        for (int k = 0; k < 8; ++k) a = fmaf(gWih[j * 17 + 8 + k], sPn[c * 8 + k], a);
        GXPdst[(gc0 + c) * 24 + j] = a;
    }
}

__global__ void __launch_bounds__(64)
k_argmax(const float* __restrict__ P, float* __restrict__ out)
{
    __shared__ float v[64];
    int t = threadIdx.x;
    v[t] = P[(960 + t) * 8];
    __syncthreads();
    if (t == 0) {
        int best = 0; float bv = v[0];
        for (int j = 1; j < 64; ++j)
            if (v[j] > bv) { bv = v[j]; best = j; }   // strict > = first-index tie-break
        out[0] = (float)best;
    }
}

extern "C" void kernel_launch(void* const* d_in, const int* in_sizes, int n_in,
                              void* d_out, int out_size, void* d_ws, size_t ws_size,
                              hipStream_t stream)
{
    const float* obs      = (const float*)d_in[0];
    const float* reward   = (const float*)d_in[1];
    const int*   A        = (const int*)d_in[2];
    const float* hidden0  = (const float*)d_in[3];
    const float* post0    = (const float*)d_in[4];
    const float* lr       = (const float*)d_in[5];
    const float* fc_in_w  = (const float*)d_in[6];
    const float* fc_in_b  = (const float*)d_in[7];
    const float* fc_hid_w = (const float*)d_in[8];
    const float* fc_hid_b = (const float*)d_in[9];
    const float* fc_out_w = (const float*)d_in[10];
    const float* fc_out_b = (const float*)d_in[11];
    const float* gin_wih  = (const float*)d_in[12];
    const float* gin_whh  = (const float*)d_in[13];
    const float* gin_bih  = (const float*)d_in[14];
    const float* gin_bhh  = (const float*)d_in[15];
    const float* ghid_wih = (const float*)d_in[16];
    const float* ghid_whh = (const float*)d_in[17];
    const float* ghid_bih = (const float*)d_in[18];
    const float* ghid_bhh = (const float*)d_in[19];
    const float* gout_wih = (const float*)d_in[20];
    const float* gout_whh = (const float*)d_in[21];
    const float* gout_bih = (const float*)d_in[22];
    const float* gout_bhh = (const float*)d_in[23];

    float* ws      = (float*)d_ws;
    float* PH      = ws;
    float* Uin     = ws + 7340032;
    float* Utop    = Uin + 524288;
    float* Urt     = Utop + 524288;
    float* Uout    = Urt + 458752;
    float* P       = Uout + 524288;
    float* GXPin1  = P + 8192;
    float* GXPhid1 = GXPin1 + 24576;
    float* GXPout  = GXPhid1 + 24576;
    float* GXPin2  = GXPout + 24576;
    float* GXPhid2 = GXPin2 + 24576;

    k_prep<<<32, 256, 0, stream>>>(obs, fc_in_w, fc_in_b, post0, P,
                                   GXPin1, GXPhid1, gin_wih, ghid_wih);

    // ---- tick 1 ----
    k_syn_in<1><<<256, 256, 0, stream>>>(A, hidden0, P, PH, Uin, Utop, Uout, GXPin1,
                                         gin_wih, gin_whh, gin_bih, gin_bhh, reward, lr);
    k_sum_hid1<<<28, 256, 0, stream>>>(PH, P, fc_hid_w, fc_hid_b,
                                       GXPhid1, GXPout, GXPin2,
                                       ghid_wih, gout_wih, gin_wih);
    k_syn_hid1<<<3584, 256, 0, stream>>>(A, hidden0, P, PH, Utop, Urt, GXPhid1,
                                         ghid_wih, ghid_whh, ghid_bih, ghid_bhh, reward, lr);
    k_sum_out<true><<<16, 256, 0, stream>>>(PH, P, fc_out_w, fc_out_b, GXPhid2, ghid_wih);
    k_syn_out<<<256, 256, 0, stream>>>(A, hidden0, P, PH, Uout, GXPout,
                                       gout_wih, gout_whh, gout_bih, gout_bhh, reward, lr);

    // ---- tick 2 (input-neuron update identical to tick1 -> skipped; out-syn dead) ----
    k_syn_in<2><<<256, 256, 0, stream>>>(A, hidden0, P, PH, Uin, Utop, Uout, GXPin2,
                                         gin_wih, gin_whh, gin_bih, gin_bhh, reward, lr);
    k_sum_full<<<112, 512, 0, stream>>>(PH, P, fc_hid_w, fc_hid_b);
    k_syn_hid2<<<224, 256, 0, stream>>>(A, hidden0, P, PH, Urt, GXPhid2,
                                        ghid_wih, ghid_whh, ghid_bih, ghid_bhh, reward, lr);
    k_sum_out<false><<<16, 256, 0, stream>>>(PH, P, fc_out_w, fc_out_b, nullptr, nullptr);

    k_argmax<<<1, 64, 0, stream>>>(P, (float*)d_out);
}

// Round 14
// 76.016 us; speedup vs baseline: 15.4595x; 1.1665x over previous
//
#include <hip/hip_runtime.h>

#define NN 1024

typedef float f32x8 __attribute__((ext_vector_type(8)));

// ---------------- workspace layout (floats) ----------------
// PH     : [896][1024][8] @ 0        (7340032)  cols<64 never written/read
// Uin    : [64][1024][8]  @ 7340032  (524288)
// Utop   : [64][1024][8]  @ 7864320  (524288)
// Urt    : [896][64][8]   @ 8388608  (458752)
// Uout   : [64][1024][8]  @ 8847360  (524288)
// P      : [1024][8]      @ 9371648  (8192)
// GXPin1 : [1024][24]     @ 9379840  gin  over P0
// GXPhid1: [1024][24]     @ 9404416  ghid over P1 (+post0 tail)
// GXPout : [1024][24]     @ 9428992  gout over P2
// GXPin2 : [1024][24]     @ 9453568  gin  over P2
// GXPhid2: [1024][24]     @ 9478144  ghid over P3 (cols 960..)

__device__ __forceinline__ float sigmoid_f(float x)
{
    return __fdividef(1.f, 1.f + __expf(-x));
}
__device__ __forceinline__ float tanh_f(float x)
{
    float ax = fabsf(x);
    float e  = __expf(-2.f * ax);
    float t  = __fdividef(1.f - e, 1.f + e);
    return copysignf(t, x);
}
__device__ __forceinline__ f32x8 ld8(const float* __restrict__ p) { return *(const f32x8*)p; }
__device__ __forceinline__ void st8(float* __restrict__ p, f32x8 v) { *(f32x8*)p = v; }

// gx = sGX[j] (row part: bias+reward+pre) + gxp[j] (col part, precomputed) ;
// gh = sBhh[j] + Whh[j]·h  (per-edge, irreducible)
__device__ __forceinline__ f32x8 gru_core(const float (*__restrict__ sWH)[8],
                                          const float* __restrict__ sGX,
                                          const float* __restrict__ sBhh,
                                          const float* __restrict__ gxp,
                                          f32x8 h, float lr)
{
    f32x8 gr = ld8(gxp), gz = ld8(gxp + 8), gn = ld8(gxp + 16);
    f32x8 upd;
#pragma unroll
    for (int d = 0; d < 8; ++d) {
        float hr = sBhh[d], hz = sBhh[8 + d], hn = sBhh[16 + d];
#pragma unroll
        for (int k = 0; k < 8; ++k) {
            hr = fmaf(sWH[d][k],      h[k], hr);
            hz = fmaf(sWH[8 + d][k],  h[k], hz);
            hn = fmaf(sWH[16 + d][k], h[k], hn);
        }
        float r  = sigmoid_f(sGX[d] + gr[d] + hr);
        float z  = sigmoid_f(sGX[8 + d] + gz[d] + hz);
        float nv = tanh_f(fmaf(r, hn, sGX[16 + d] + gn[d]));
        float g  = (1.f - z) * nv + z * h[d];
        upd[d] = fmaf(g, lr, h[d]);
    }
    return upd;
}

#define SYN_STAGE(PREROW)                                                               \
    __shared__ float sWH[24][8]; __shared__ float sGX[24]; __shared__ float sBhh[24];   \
    { int t_ = threadIdx.x;                                                             \
      if (t_ < 192) { int j = t_ >> 3, k = t_ & 7; sWH[j][k] = Whh[j * 8 + k]; }        \
      else if (t_ < 216) { int j = t_ - 192;                                            \
        float a = Bih[j] + Wih[j * 17 + 16] * reward[0];                                \
        _Pragma("unroll") for (int k = 0; k < 8; ++k)                                   \
            a = fmaf(Wih[j * 17 + k], P[(PREROW) * 8 + k], a);                          \
        sGX[j] = a; sBhh[j] = Bhh[j]; }                                                 \
      __syncthreads(); }

// P init + GXPin1 (gin over P0) + GXPhid1 tail (ghid over post0, cols 960..)
__global__ void __launch_bounds__(256)
k_prep(const float* __restrict__ obs, const float* __restrict__ fiw,
       const float* __restrict__ fib, const float* __restrict__ post0,
       float* __restrict__ P, float* __restrict__ GXPin1, float* __restrict__ GXPhid1,
       const float* __restrict__ gin_wih, const float* __restrict__ ghid_wih)
{
    int t = threadIdx.x, b = blockIdx.x;
    int gid = b * 256 + t;
    float pv;
    if (gid < 512) {
        int i = gid >> 3, j = gid & 7;
        float rs = 0.f;
#pragma unroll
        for (int d = 0; d < 8; ++d) rs += fiw[j * 8 + d];
        pv = tanhf(obs[i] * rs + fib[j]);
    } else {
        pv = post0[gid];
    }
    P[gid] = pv;
    __shared__ float sP[256];
    sP[t] = pv;
    __syncthreads();
    int c0 = b * 32;
    const float* W = nullptr; float* dst = nullptr;
    if (c0 >= 64 && c0 < 960) { W = gin_wih;  dst = GXPin1; }
    else if (c0 >= 960)       { W = ghid_wih; dst = GXPhid1; }
    if (dst) {
        for (int v = t; v < 768; v += 256) {
            int c = v / 24, j = v % 24;
            float a = 0.f;
#pragma unroll
            for (int k = 0; k < 8; ++k) a = fmaf(W[j * 17 + 8 + k], sP[c * 8 + k], a);
            dst[(c0 + c) * 24 + j] = a;
        }
    }
}

// input-layer syn: row r=bid>>2 (<64), cols 64..1024. TICK1 zero-fills inactive.
template <int TICK>
__global__ void __launch_bounds__(256, 4)
k_syn_in(const int* __restrict__ A, const float* __restrict__ hidden0,
         const float* __restrict__ P, float* __restrict__ PH,
         float* __restrict__ Uin, const float* __restrict__ Utop,
         const float* __restrict__ Uout, const float* __restrict__ GXP,
         const float* __restrict__ Wih, const float* __restrict__ Whh,
         const float* __restrict__ Bih, const float* __restrict__ Bhh,
         const float* __restrict__ reward, const float* __restrict__ lr)
{
    int r = blockIdx.x >> 2;
    SYN_STAGE(r);
    int n = 64 + ((blockIdx.x & 3) << 8) + threadIdx.x;
    if (n >= NN) return;
    int e = (r * NN + n) * 8;
    if (!A[r * NN + n]) {
        if (TICK == 1) { f32x8 z{}; st8(PH + e, z); }
        return;
    }
    f32x8 h;
    if (TICK == 1) {
        h = ld8(hidden0 + e);
    } else {
        const float* src = Uin + e;
        if (A[(960 + r) * NN + n])     src = Uout + e;
        else if (A[(64 + r) * NN + n]) src = Utop + e;
        h = ld8(src);
    }
    f32x8 upd = gru_core(sWH, sGX, sBhh, GXP + n * 24, h, lr[0]);
    f32x8 pre = ld8(P + r * 8);
    st8(PH + e, upd * pre);
    if (TICK == 1) st8(Uin + e, upd);
}

// hidden syn tick1: row l=bid>>2 (<896), cols 64..1024.
// l<64 skip-if-inactive (preserve in-syn); l>=64 zero-if-inactive.
__global__ void __launch_bounds__(256, 4)
k_syn_hid1(const int* __restrict__ A, const float* __restrict__ hidden0,
           const float* __restrict__ P, float* __restrict__ PH,
           float* __restrict__ Utop, float* __restrict__ Urt,
           const float* __restrict__ GXP,
           const float* __restrict__ Wih, const float* __restrict__ Whh,
           const float* __restrict__ Bih, const float* __restrict__ Bhh,
           const float* __restrict__ reward, const float* __restrict__ lr)
{
    int l = blockIdx.x >> 2;
    SYN_STAGE(64 + l);
    int n = 64 + ((blockIdx.x & 3) << 8) + threadIdx.x;
    if (n >= NN) return;
    int e = (l * NN + n) * 8;
    if (!A[(64 + l) * NN + n]) {
        if (l >= 64) { f32x8 z{}; st8(PH + e, z); }
        return;
    }
    f32x8 h = ld8(hidden0 + ((64 + l) * NN + n) * 8);
    f32x8 upd = gru_core(sWH, sGX, sBhh, GXP + n * 24, h, lr[0]);
    f32x8 pre = ld8(P + (64 + l) * 8);
    st8(PH + e, upd * pre);
    if (l < 64) st8(Utop + e, upd);
    if (n >= 960) st8(Urt + (l * 64 + (n - 960)) * 8, upd);
}

// output syn tick1: row 960+l, writes PH rows l<64; skip-if-inactive.
__global__ void __launch_bounds__(256, 4)
k_syn_out(const int* __restrict__ A, const float* __restrict__ hidden0,
          const float* __restrict__ P, float* __restrict__ PH,
          float* __restrict__ Uout, const float* __restrict__ GXP,
          const float* __restrict__ Wih, const float* __restrict__ Whh,
          const float* __restrict__ Bih, const float* __restrict__ Bhh,
          const float* __restrict__ reward, const float* __restrict__ lr)
{
    int l = blockIdx.x >> 2;
    SYN_STAGE(960 + l);
    int n = 64 + ((blockIdx.x & 3) << 8) + threadIdx.x;
    if (n >= NN) return;
    if (!A[(960 + l) * NN + n]) return;
    f32x8 h = ld8(hidden0 + ((960 + l) * NN + n) * 8);
    f32x8 upd = gru_core(sWH, sGX, sBhh, GXP + n * 24, h, lr[0]);
    f32x8 pre = ld8(P + (960 + l) * 8);
    int e = (l * NN + n) * 8;
    st8(PH + e, upd * pre);
    st8(Uout + e, upd);
}

// hidden syn tick2: rows 0..896, cols 960..1024 only; skip-if-inactive. 4 rows/block.
__global__ void __launch_bounds__(256, 4)
k_syn_hid2(const int* __restrict__ A, const float* __restrict__ hidden0,
           const float* __restrict__ P, float* __restrict__ PH,
           const float* __restrict__ Urt, const float* __restrict__ GXP,
           const float* __restrict__ Wih, const float* __restrict__ Whh,
           const float* __restrict__ Bih, const float* __restrict__ Bhh,
           const float* __restrict__ reward, const float* __restrict__ lr)
{
    __shared__ float sWH[24][8]; __shared__ float sBhh[24]; __shared__ float sGX4[4][24];
    int t = threadIdx.x;
    if (t < 192) { int j = t >> 3, k = t & 7; sWH[j][k] = Whh[j * 8 + k]; }
    else if (t < 216) sBhh[t - 192] = Bhh[t - 192];
    if (t < 96) {
        int rr = t / 24, j = t % 24;
        int l = blockIdx.x * 4 + rr;
        float a = Bih[j] + Wih[j * 17 + 16] * reward[0];
#pragma unroll
        for (int k = 0; k < 8; ++k) a = fmaf(Wih[j * 17 + k], P[(64 + l) * 8 + k], a);
        sGX4[rr][j] = a;
    }
    __syncthreads();
    int rr = t >> 6, nn = t & 63;
    int l = blockIdx.x * 4 + rr, n = 960 + nn;
    if (!A[(64 + l) * NN + n]) return;
    const float* hp = (l < 832 && A[(128 + l) * NN + n]) ? (Urt + ((64 + l) * 64 + nn) * 8)
                                                         : (hidden0 + ((64 + l) * NN + n) * 8);
    f32x8 h = ld8(hp);
    f32x8 upd = gru_core(sWH, sGX4[rr], sBhh, GXP + n * 24, h, lr[0]);
    f32x8 pre = ld8(P + (64 + l) * 8);
    st8(PH + (l * NN + n) * 8, upd * pre);
}

// tick1 hidden neuron: sum PH rows 0..64, cols 64..960; fused neuron + 3x GXP production.
__global__ void __launch_bounds__(256)
k_sum_hid1(const float* __restrict__ PH, float* __restrict__ P,
           const float* __restrict__ W, const float* __restrict__ b,
           float* __restrict__ GXPhid1, float* __restrict__ GXPout,
           float* __restrict__ GXPin2,
           const float* __restrict__ ghid_wih, const float* __restrict__ gout_wih,
           const float* __restrict__ gin_wih)
{
    int t = threadIdx.x;
    int c0 = 64 + blockIdx.x * 32;
    int base = c0 * 8 + t;
    float acc = 0.f;
    for (int r = 0; r < 64; ++r) acc += PH[r * 8192 + base];
    __shared__ float sS[256];
    sS[t] = acc; __syncthreads();
    int j = t & 7;
    float z = b[j];
#pragma unroll
    for (int d = 0; d < 8; ++d) z = fmaf(sS[(t & ~7) | d], W[j * 8 + d], z);
    float pv = tanhf(z);
    P[base] = pv;
    __shared__ float sP[256];
    sP[t] = pv; __syncthreads();
    for (int v = t; v < 768; v += 256) {
        int c = v / 24, jj = v % 24;
        float a1 = 0.f, a2 = 0.f, a3 = 0.f;
#pragma unroll
        for (int k = 0; k < 8; ++k) {
            float p = sP[c * 8 + k];
            a1 = fmaf(ghid_wih[jj * 17 + 8 + k], p, a1);
            a2 = fmaf(gout_wih[jj * 17 + 8 + k], p, a2);
            a3 = fmaf(gin_wih [jj * 17 + 8 + k], p, a3);
        }
        int o = (c0 + c) * 24 + jj;
        GXPhid1[o] = a1; GXPout[o] = a2; GXPin2[o] = a3;
    }
}

// generic 896-row column sum + neuron (8 cols/block, 512 thr = 8c x 8d x 8 chunks),
// optional fused GXP production.
template <bool DO_GXP>
__global__ void __launch_bounds__(512)
k_sumN(const float* __restrict__ PH, float* __restrict__ P,
       const float* __restrict__ W, const float* __restrict__ b,
       int col0, float* __restrict__ GXPdst, const float* __restrict__ gWih)
{
    int t = threadIdx.x;
    int col = (t >> 3) & 7, dim = t & 7, chunk = t >> 6;
    int gc0 = col0 + blockIdx.x * 8;
    float acc = 0.f;
    int base = (gc0 + col) * 8 + dim;
    for (int r = chunk * 112; r < chunk * 112 + 112; ++r) acc += PH[r * 8192 + base];
    __shared__ float sA[8][64];
    sA[chunk][(col << 3) | dim] = acc;
    __syncthreads();
    __shared__ float sS[64];
    if (t < 64) {
        float s = 0.f;
#pragma unroll
        for (int c = 0; c < 8; ++c) s += sA[c][t];
        sS[t] = s;
    }
    __syncthreads();
    __shared__ float sPn[64];
    if (t < 64) {
        int cl = t >> 3, j = t & 7;
        float z = b[j];
#pragma unroll
        for (int d = 0; d < 8; ++d) z = fmaf(sS[(cl << 3) | d], W[j * 8 + d], z);
        float pv = tanhf(z);
        P[(gc0 + cl) * 8 + j] = pv;
        sPn[t] = pv;
    }
    __syncthreads();
    if (DO_GXP && t < 192) {
        int c = t / 24, j = t % 24;
        float a = 0.f;
#pragma unroll
        for (int k = 0; k < 8; ++k) a = fmaf(gWih[j * 17 + 8 + k], sPn[c * 8 + k], a);
        GXPdst[(gc0 + c) * 24 + j] = a;
    }
}

__global__ void __launch_bounds__(64)
k_argmax(const float* __restrict__ P, float* __restrict__ out)
{
    __shared__ float v[64];
    int t = threadIdx.x;
    v[t] = P[(960 + t) * 8];
    __syncthreads();
    if (t == 0) {
        int best = 0; float bv = v[0];
        for (int j = 1; j < 64; ++j)
            if (v[j] > bv) { bv = v[j]; best = j; }   // strict > = first-index tie-break
        out[0] = (float)best;
    }
}

extern "C" void kernel_launch(void* const* d_in, const int* in_sizes, int n_in,
                              void* d_out, int out_size, void* d_ws, size_t ws_size,
                              hipStream_t stream)
{
    const float* obs      = (const float*)d_in[0];
    const float* reward   = (const float*)d_in[1];
    const int*   A        = (const int*)d_in[2];
    const float* hidden0  = (const float*)d_in[3];
    const float* post0    = (const float*)d_in[4];
    const float* lr       = (const float*)d_in[5];
    const float* fc_in_w  = (const float*)d_in[6];
    const float* fc_in_b  = (const float*)d_in[7];
    const float* fc_hid_w = (const float*)d_in[8];
    const float* fc_hid_b = (const float*)d_in[9];
    const float* fc_out_w = (const float*)d_in[10];
    const float* fc_out_b = (const float*)d_in[11];
    const float* gin_wih  = (const float*)d_in[12];
    const float* gin_whh  = (const float*)d_in[13];
    const float* gin_bih  = (const float*)d_in[14];
    const float* gin_bhh  = (const float*)d_in[15];
    const float* ghid_wih = (const float*)d_in[16];
    const float* ghid_whh = (const float*)d_in[17];
    const float* ghid_bih = (const float*)d_in[18];
    const float* ghid_bhh = (const float*)d_in[19];
    const float* gout_wih = (const float*)d_in[20];
    const float* gout_whh = (const float*)d_in[21];
    const float* gout_bih = (const float*)d_in[22];
    const float* gout_bhh = (const float*)d_in[23];

    float* ws      = (float*)d_ws;
    float* PH      = ws;
    float* Uin     = ws + 7340032;
    float* Utop    = Uin + 524288;
    float* Urt     = Utop + 524288;
    float* Uout    = Urt + 458752;
    float* P       = Uout + 524288;
    float* GXPin1  = P + 8192;
    float* GXPhid1 = GXPin1 + 24576;
    float* GXPout  = GXPhid1 + 24576;
    float* GXPin2  = GXPout + 24576;
    float* GXPhid2 = GXPin2 + 24576;

    k_prep<<<32, 256, 0, stream>>>(obs, fc_in_w, fc_in_b, post0, P,
                                   GXPin1, GXPhid1, gin_wih, ghid_wih);

    // ---- tick 1 ----
    k_syn_in<1><<<256, 256, 0, stream>>>(A, hidden0, P, PH, Uin, Utop, Uout, GXPin1,
                                         gin_wih, gin_whh, gin_bih, gin_bhh, reward, lr);
    k_sum_hid1<<<28, 256, 0, stream>>>(PH, P, fc_hid_w, fc_hid_b,
                                       GXPhid1, GXPout, GXPin2,
                                       ghid_wih, gout_wih, gin_wih);
    k_syn_hid1<<<3584, 256, 0, stream>>>(A, hidden0, P, PH, Utop, Urt, GXPhid1,
                                         ghid_wih, ghid_whh, ghid_bih, ghid_bhh, reward, lr);
    k_sumN<true><<<8, 512, 0, stream>>>(PH, P, fc_out_w, fc_out_b, 960, GXPhid2, ghid_wih);
    k_syn_out<<<256, 256, 0, stream>>>(A, hidden0, P, PH, Uout, GXPout,
                                       gout_wih, gout_whh, gout_bih, gout_bhh, reward, lr);

    // ---- tick 2 (input-neuron update identical to tick1 -> skipped; out-syn dead) ----
    k_syn_in<2><<<256, 256, 0, stream>>>(A, hidden0, P, PH, Uin, Utop, Uout, GXPin2,
                                         gin_wih, gin_whh, gin_bih, gin_bhh, reward, lr);
    k_sumN<false><<<112, 512, 0, stream>>>(PH, P, fc_hid_w, fc_hid_b, 64, nullptr, nullptr);
    k_syn_hid2<<<224, 256, 0, stream>>>(A, hidden0, P, PH, Urt, GXPhid2,
                                        ghid_wih, ghid_whh, ghid_bih, ghid_bhh, reward, lr);
    k_sumN<false><<<8, 512, 0, stream>>>(PH, P, fc_out_w, fc_out_b, 960, nullptr, nullptr);

    k_argmax<<<1, 64, 0, stream>>>(P, (float*)d_out);
}